// Round 15
// baseline (76.054 us; speedup 1.0000x reference)
//
#include <hip/hip_runtime.h>

#define NN 1024
#define DD 128
#define LDU 36  // uT k-stride in phase 2 (floats): 144B, 16B-aligned

// ---- fast math helpers ----
// v_rcp_f32 is ~1 ulp on gfx950; NO Newton step (NR turns inf into NaN).
__device__ __forceinline__ float frcp(float x) {
  return __builtin_amdgcn_rcpf(x);
}
__device__ __forceinline__ float fsqrt(float x) {
  return __builtin_amdgcn_sqrtf(x);
}
// artanh(z)/z with reference-style clipping (z >= 0)
__device__ __forceinline__ float artanh_ratio(float z) {
  z = fminf(z, 1.0f - 1e-7f);
  if (z < 1e-4f) return 1.0f + z * z * (1.0f / 3.0f);
  return 0.5f * (__logf(1.0f + z) - __logf(1.0f - z)) * frcp(z);
}
// tanh(a) for a >= 0 via exp(-2a) in [0,1]: overflow-free, saturates to 1.
__device__ __forceinline__ float ftanh(float a) {
  const float e = __expf(-2.0f * a);
  return (1.0f - e) * frcp(1.0f + e);
}

// Grid barrier: increment once (RMW), then SPIN ON A LOAD (not RMW!).
// R14's atomicAdd(cnt,0) poll serialized 256 RMWs per round at one L2
// slice (~25 us/barrier). Agent-scope relaxed loads are read-shared.
__device__ __forceinline__ void grid_barrier(unsigned* cnt, unsigned target) {
  __syncthreads();
  if (threadIdx.x == 0) {
    __threadfence();                 // release: W/Vp/PA visible before count
    atomicAdd(cnt, 1u);
    while (__hip_atomic_load(cnt, __ATOMIC_RELAXED, __HIP_MEMORY_SCOPE_AGENT) < target)
      __builtin_amdgcn_s_sleep(2);
    __threadfence();                 // acquire side
  }
  __syncthreads();
}

// ---------------- MEGA: k2 -> barrier -> k3 -> barrier -> k4 ----------------
// Grid 256 x 256. All 256 blocks co-resident (1 block/CU on 256 CUs).
// Phase bodies byte-identical to the proven R11 k2 / k3 / k4.
__global__ __launch_bounds__(256) void mega(
    const float* __restrict__ x, const float* __restrict__ adj,
    const float* __restrict__ aw, const float* __restrict__ bptr,
    float* __restrict__ W, float* __restrict__ Vp, float* __restrict__ PA,
    unsigned* __restrict__ cnt, float* __restrict__ out) {
  __shared__ __align__(16) float arena[16640];  // 65 KB, shared by phases
  const int t = threadIdx.x;
  const int blk = blockIdx.x;

  // ================= Phase 1: S-GEMM + pair epilogue (proven k2) =========
  {
    float* xiT = arena;             // [DD*64]
    float* xjT = arena + 8192;      // [DD*64]
    float* s_nx2i = arena + 16384;  // [64]
    float* s_lft = arena + 16448;
    float* s_nx2j = arena + 16512;
    float* s_rgt = arena + 16576;
    const int bi = blk >> 4, bj = blk & 15;
    const int tx = t & 15, ty = t >> 4;
    const int gi0 = bi * 64 + ty * 4;
    const int gj0 = bj * 64 + tx * 4;

    float4 ajv[4];
#pragma unroll
    for (int i = 0; i < 4; ++i)
      ajv[i] = *(const float4*)&adj[(size_t)(gi0 + i) * NN + gj0];
    const float attb = bptr[0];

    {
      const int r = t & 63;
      const int kq = t >> 6;
      const float* si = x + (bi * 64 + r) * DD + kq * 32;
      const float* sj = x + (bj * 64 + r) * DD + kq * 32;
#pragma unroll
      for (int m = 0; m < 8; ++m) {
        const int k0 = kq * 32 + m * 4;
        const float4 vi = *(const float4*)(si + m * 4);
        const float4 vj = *(const float4*)(sj + m * 4);
        xiT[(k0 + 0) * 64 + r] = vi.x;
        xiT[(k0 + 1) * 64 + r] = vi.y;
        xiT[(k0 + 2) * 64 + r] = vi.z;
        xiT[(k0 + 3) * 64 + r] = vi.w;
        xjT[(k0 + 0) * 64 + r] = vj.x;
        xjT[(k0 + 1) * 64 + r] = vj.y;
        xjT[(k0 + 2) * 64 + r] = vj.z;
        xjT[(k0 + 3) * 64 + r] = vj.w;
      }
    }
    __syncthreads();

    // per-node scalars from staged panels
    {
      const int r = (t >> 1) & 63;
      const int h = t & 1;
      const bool jp = (t >= 128);
      const float* panel = jp ? xjT : xiT;
      const float* wv = aw + (jp ? DD : 0);
      float sa = 0.0f, sb = 0.0f;
      const int k0 = h * 64;
#pragma unroll 8
      for (int k = 0; k < 64; ++k) {
        const float v = panel[(k0 + k) * 64 + r];
        sa = fmaf(v, v, sa);
        sb = fmaf(v, wv[k0 + k], sb);
      }
      sa += __shfl_xor(sa, 1, 64);
      sb += __shfl_xor(sb, 1, 64);
      if (h == 0) {
        const float pn = fmaxf(fsqrt(sa), 1e-15f);
        const float hh = artanh_ratio(pn);
        if (jp) { s_nx2j[r] = sa; s_rgt[r] = hh * sb; }
        else    { s_nx2i[r] = sa; s_lft[r] = hh * sb; }
      }
    }
    __syncthreads();

    float acc[4][4] = {};
#pragma unroll 2
    for (int kb = 0; kb < DD; kb += 4) {
      float4 A[4], B[4];
#pragma unroll
      for (int q = 0; q < 4; ++q) {
        A[q] = *(const float4*)&xiT[(kb + q) * 64 + ty * 4];
        B[q] = *(const float4*)&xjT[(kb + q) * 64 + tx * 4];
      }
#pragma unroll
      for (int q = 0; q < 4; ++q) {
        const float aa[4] = {A[q].x, A[q].y, A[q].z, A[q].w};
        const float bb[4] = {B[q].x, B[q].y, B[q].z, B[q].w};
#pragma unroll
        for (int i = 0; i < 4; ++i)
#pragma unroll
          for (int j = 0; j < 4; ++j) acc[i][j] = fmaf(aa[i], bb[j], acc[i][j]);
      }
    }
    float ny2v[4], rv[4];
#pragma unroll
    for (int j = 0; j < 4; ++j) {
      ny2v[j] = s_nx2j[tx * 4 + j];
      rv[j] = s_rgt[tx * 4 + j];
    }
    float sua[4];
#pragma unroll
    for (int i = 0; i < 4; ++i) {
      const float xi2 = s_nx2i[ty * 4 + i];
      const float li = s_lft[ty * 4 + i];
      const float beta = 1.0f - xi2;
      const float betac = fmaxf(beta, 1e-15f);
      const float av[4] = {ajv[i].x, ajv[i].y, ajv[i].z, ajv[i].w};
      float u4[4];
      float ua = 0.0f;
#pragma unroll
      for (int j = 0; j < 4; ++j) {
        const float s = acc[i][j];
        const float al = 1.0f - 2.0f * s + ny2v[j];
        const float den = fmaxf(1.0f - 2.0f * s + xi2 * ny2v[j], 1e-15f);
        const float rden = frcp(den);
        float s2 = fmaxf(al * al * xi2 - 2.0f * al * beta * s + beta * beta * ny2v[j], 0.0f);
        s2 = s2 * rden * rden;
        const float sn = fmaxf(fsqrt(s2), 1e-15f);
        const float G = betac * artanh_ratio(sn);
        const float sig = frcp(1.0f + __expf(-(li + rv[j] + attb)));
        const float u = sig * av[j] * G * rden;
        u4[j] = u;
        ua = fmaf(u, al, ua);
      }
      float4 st; st.x = u4[0]; st.y = u4[1]; st.z = u4[2]; st.w = u4[3];
      *(float4*)&W[(size_t)(gi0 + i) * NN + gj0] = st;
      sua[i] = ua;
    }
#pragma unroll
    for (int m = 1; m < 16; m <<= 1) {
#pragma unroll
      for (int i = 0; i < 4; ++i) sua[i] += __shfl_xor(sua[i], m, 64);
    }
    if (tx == 0) {
#pragma unroll
      for (int i = 0; i < 4; ++i) PA[(gi0 + i) * 16 + bj] = sua[i];
    }
  }

  grid_barrier(cnt, 256u);

  // ================= Phase 2: V-partials GEMM (proven k3) ================
  {
    float* uT = arena;         // [128*LDU]
    float* xT = arena + 4608;  // [64*DD]
    const int kt = blk & 7, rt = blk >> 3;
    {
      const int r = t >> 3;
      const int c0 = (t & 7) * 16;
      const float* wrow = &W[(size_t)(rt * 32 + r) * NN + kt * 128 + c0];
#pragma unroll
      for (int m = 0; m < 4; ++m) {
        const float4 v = *(const float4*)(wrow + m * 4);
        uT[(c0 + m * 4 + 0) * LDU + r] = v.x;
        uT[(c0 + m * 4 + 1) * LDU + r] = v.y;
        uT[(c0 + m * 4 + 2) * LDU + r] = v.z;
        uT[(c0 + m * 4 + 3) * LDU + r] = v.w;
      }
    }
    const int tx = t & 31, ty = t >> 5;
    float acc[4][4] = {};
    for (int jh = 0; jh < 2; ++jh) {
      __syncthreads();
      {
        const float* xsrc = &x[(size_t)(kt * 128 + jh * 64) * DD];
#pragma unroll
        for (int p = 0; p < 8; ++p) {
          *(float4*)&xT[p * 1024 + t * 4] = *(const float4*)&xsrc[p * 1024 + t * 4];
        }
      }
      __syncthreads();
#pragma unroll 2
      for (int kb = 0; kb < 64; kb += 4) {
        float4 A[4], B[4];
#pragma unroll
        for (int q = 0; q < 4; ++q) {
          A[q] = *(const float4*)&uT[(jh * 64 + kb + q) * LDU + ty * 4];
          B[q] = *(const float4*)&xT[(kb + q) * DD + tx * 4];
        }
#pragma unroll
        for (int q = 0; q < 4; ++q) {
          const float aa[4] = {A[q].x, A[q].y, A[q].z, A[q].w};
          const float bb[4] = {B[q].x, B[q].y, B[q].z, B[q].w};
#pragma unroll
          for (int i = 0; i < 4; ++i)
#pragma unroll
            for (int j = 0; j < 4; ++j) acc[i][j] = fmaf(aa[i], bb[j], acc[i][j]);
        }
      }
    }
    const int row0 = rt * 32 + ty * 4;
#pragma unroll
    for (int i = 0; i < 4; ++i) {
      float4 s; s.x = acc[i][0]; s.y = acc[i][1]; s.z = acc[i][2]; s.w = acc[i][3];
      *(float4*)&Vp[((size_t)kt * NN + row0 + i) * DD + tx * 4] = s;
    }
  }

  grid_barrier(cnt, 512u);

  // ================= Phase 3: reduce + expmap/proj (proven k4) ===========
  {
    const int w = t >> 6;
    const int l = t & 63;
    const int row = blk * 4 + w;

    const float2 xv = *(const float2*)&x[row * DD + 2 * l];
    const float xi0 = xv.x, xi1 = xv.y;
    float ra = xi0 * xi0 + xi1 * xi1;
#pragma unroll
    for (int m = 1; m < 64; m <<= 1) ra += __shfl_xor(ra, m, 64);
    const float nx2i = ra;

    float v0 = 0.0f, v1 = 0.0f;
#pragma unroll
    for (int kt = 0; kt < 8; ++kt) {
      const float2 vv = *(const float2*)&Vp[((size_t)kt * NN + row) * DD + 2 * l];
      v0 += vv.x;
      v1 += vv.y;
    }
    float sa = (l < 16) ? PA[row * 16 + l] : 0.0f;
#pragma unroll
    for (int m = 1; m < 64; m <<= 1) sa += __shfl_xor(sa, m, 64);

    const float beta = 1.0f - nx2i;
    const float betac = fmaxf(beta, 1e-15f);
    const float u0 = beta * v0 - sa * xi0;
    const float u1 = beta * v1 - sa * xi1;
    float p0 = u0 * u0 + u1 * u1;
    float p1 = xi0 * u0 + xi1 * u1;
#pragma unroll
    for (int m = 1; m < 64; m <<= 1) {
      p0 += __shfl_xor(p0, m, 64);
      p1 += __shfl_xor(p1, m, 64);
    }
    const float un = fmaxf(fsqrt(p0), 1e-15f);
    const float tau = ftanh(frcp(betac) * un) * frcp(un);
    const float y2 = tau * tau * p0;
    const float xy = tau * p1;
    const float numx = 1.0f + 2.0f * xy + y2;
    const float dene = fmaxf(1.0f + 2.0f * xy + nx2i * y2, 1e-15f);
    const float rdene = frcp(dene);
    float r0 = (numx * xi0 + beta * tau * u0) * rdene;
    float r1 = (numx * xi1 + beta * tau * u1) * rdene;
    const float n2 = fmaxf(numx * numx * nx2i + 2.0f * numx * beta * xy + beta * beta * y2, 0.0f);
    const float n = fmaxf(fsqrt(n2) * rdene, 1e-15f);
    const float maxn = 1.0f - 4e-3f;
    if (n > maxn) {
      const float sc = maxn * frcp(n);
      r0 *= sc;
      r1 *= sc;
    }
    float2 ro; ro.x = r0; ro.y = r1;
    *(float2*)&out[row * DD + 2 * l] = ro;
  }
}

// ---------------- Fallback: fused kernel (proven structure) ----------------
__global__ __launch_bounds__(256) void hypagg_fused(
    const float* __restrict__ x, const float* __restrict__ adj,
    const float* __restrict__ aw, const float* __restrict__ bptr,
    float* __restrict__ out) {
  __shared__ __align__(16) float xi_lds[4 * DD];
  __shared__ __align__(16) float w2_lds[DD];
  const int t = threadIdx.x;
  const int w = t >> 6;
  const int l = t & 63;
  const int row = blockIdx.x * 4 + w;

  xi_lds[t] = x[blockIdx.x * 4 * DD + t];
  xi_lds[t + 256] = x[blockIdx.x * 4 * DD + t + 256];
  if (t < DD) w2_lds[t] = aw[DD + t];
  __syncthreads();

  const float attb = bptr[0];
  const float* xi = &xi_lds[w * DD];
  const float xi0 = xi[l];
  const float xi1 = xi[l + 64];

  float ra = xi0 * xi0 + xi1 * xi1;
  float rb = xi0 * aw[l] + xi1 * aw[l + 64];
#pragma unroll
  for (int m = 1; m < 64; m <<= 1) {
    ra += __shfl_xor(ra, m, 64);
    rb += __shfl_xor(rb, m, 64);
  }
  const float nx2i = ra;
  const float beta = 1.0f - nx2i;
  const float betac = fmaxf(beta, 1e-15f);
  const float hi = artanh_ratio(fmaxf(fsqrt(nx2i), 1e-15f));
  const float lfti = hi * rb;

  float V0 = 0.0f, V1 = 0.0f, SA = 0.0f;

  for (int j0 = 0; j0 < NN; j0 += 64) {
    const int jj = j0 + l;
    const float* xj = x + jj * DD;
    float s = 0.0f, ny2 = 0.0f, rj = 0.0f;
#pragma unroll 8
    for (int k4 = 0; k4 < DD / 4; ++k4) {
      const float4 b4 = *(const float4*)(xj + k4 * 4);
      const float4 a4 = *(const float4*)(xi + k4 * 4);
      const float4 w4 = *(const float4*)(&w2_lds[k4 * 4]);
      s   = fmaf(a4.x, b4.x, fmaf(a4.y, b4.y, fmaf(a4.z, b4.z, fmaf(a4.w, b4.w, s))));
      ny2 = fmaf(b4.x, b4.x, fmaf(b4.y, b4.y, fmaf(b4.z, b4.z, fmaf(b4.w, b4.w, ny2))));
      rj  = fmaf(w4.x, b4.x, fmaf(w4.y, b4.y, fmaf(w4.z, b4.z, fmaf(w4.w, b4.w, rj))));
    }
    const float hj = artanh_ratio(fmaxf(fsqrt(ny2), 1e-15f));
    const float rgtj = hj * rj;
    const float al = 1.0f - 2.0f * s + ny2;
    const float den = fmaxf(1.0f - 2.0f * s + nx2i * ny2, 1e-15f);
    const float rden = frcp(den);
    float s2 = fmaxf(al * al * nx2i - 2.0f * al * beta * s + beta * beta * ny2, 0.0f);
    s2 = s2 * rden * rden;
    const float sn = fmaxf(fsqrt(s2), 1e-15f);
    const float G = betac * artanh_ratio(sn);
    const float sig = frcp(1.0f + __expf(-(lfti + rgtj + attb)));
    const float u = sig * adj[row * NN + jj] * G * rden;
    SA = fmaf(u, al, SA);
#pragma unroll 16
    for (int jq = 0; jq < 64; ++jq) {
      const float uq = __shfl(u, jq, 64);
      const float xd0 = x[(j0 + jq) * DD + l];
      const float xd1 = x[(j0 + jq) * DD + l + 64];
      V0 = fmaf(uq, xd0, V0);
      V1 = fmaf(uq, xd1, V1);
    }
  }

#pragma unroll
  for (int m = 1; m < 64; m <<= 1) SA += __shfl_xor(SA, m, 64);

  const float u0 = beta * V0 - SA * xi0;
  const float u1 = beta * V1 - SA * xi1;
  float p0 = u0 * u0 + u1 * u1;
  float p1 = xi0 * u0 + xi1 * u1;
#pragma unroll
  for (int m = 1; m < 64; m <<= 1) {
    p0 += __shfl_xor(p0, m, 64);
    p1 += __shfl_xor(p1, m, 64);
  }
  const float un = fmaxf(fsqrt(p0), 1e-15f);
  const float tau = ftanh(frcp(betac) * un) * frcp(un);
  const float y2 = tau * tau * p0;
  const float xy = tau * p1;
  const float numx = 1.0f + 2.0f * xy + y2;
  const float dene = fmaxf(1.0f + 2.0f * xy + nx2i * y2, 1e-15f);
  const float rdene = frcp(dene);
  float r0 = (numx * xi0 + beta * tau * u0) * rdene;
  float r1 = (numx * xi1 + beta * tau * u1) * rdene;
  const float n2 = fmaxf(numx * numx * nx2i + 2.0f * numx * beta * xy + beta * beta * y2, 0.0f);
  const float n = fmaxf(fsqrt(n2) * rdene, 1e-15f);
  const float maxn = 1.0f - 4e-3f;
  if (n > maxn) {
    const float sc = maxn * frcp(n);
    r0 *= sc;
    r1 *= sc;
  }
  out[row * DD + l] = r0;
  out[row * DD + l + 64] = r1;
}

extern "C" void kernel_launch(void* const* d_in, const int* in_sizes, int n_in,
                              void* d_out, int out_size, void* d_ws, size_t ws_size,
                              hipStream_t stream) {
  // Bind inputs BY SIZE (unique: x=131072, adj=1048576, att_w=256, att_b=1)
  const float* x = nullptr;
  const float* adj = nullptr;
  const float* aw = nullptr;
  const float* ab = nullptr;
  for (int i = 0; i < n_in; ++i) {
    switch (in_sizes[i]) {
      case NN * DD:  x   = (const float*)d_in[i]; break;
      case NN * NN:  adj = (const float*)d_in[i]; break;
      case 2 * DD:   aw  = (const float*)d_in[i]; break;
      case 1:        ab  = (const float*)d_in[i]; break;
      default: break;
    }
  }
  float* out = (float*)d_out;

  // ws layout: W [N*N] | Vp [8*N*D] | PA [N*16] | counter [1 u32]
  const size_t need = ((size_t)NN * NN + 8 * (size_t)NN * DD + NN * 16) * sizeof(float) + sizeof(unsigned);
  if (ws_size >= need) {
    float* W  = (float*)d_ws;
    float* Vp = W + (size_t)NN * NN;
    float* PA = Vp + 8 * (size_t)NN * DD;
    unsigned* cnt = (unsigned*)(PA + NN * 16);
    hipMemsetAsync((void*)cnt, 0, sizeof(unsigned), stream);
    hipLaunchKernelGGL(mega, dim3(256), dim3(256), 0, stream,
                       x, adj, aw, ab, W, Vp, PA, cnt, out);
  } else {
    hipLaunchKernelGGL(hypagg_fused, dim3(NN / 4), dim3(256), 0, stream,
                       x, adj, aw, ab, out);
  }
}

// Round 16
// 34.174 us; speedup vs baseline: 2.2255x; 2.2255x over previous
//
#include <hip/hip_runtime.h>

#define NN 1024
#define DD 128
#define LDU 36  // uT k-stride in k3 (floats): 144B, 16B-aligned

// ---- fast math helpers ----
// v_rcp_f32 is ~1 ulp on gfx950; NO Newton step (NR turns inf into NaN).
__device__ __forceinline__ float frcp(float x) {
  return __builtin_amdgcn_rcpf(x);
}
__device__ __forceinline__ float fsqrt(float x) {
  return __builtin_amdgcn_sqrtf(x);
}
// artanh(z)/z with reference-style clipping (z >= 0)
__device__ __forceinline__ float artanh_ratio(float z) {
  z = fminf(z, 1.0f - 1e-7f);
  if (z < 1e-4f) return 1.0f + z * z * (1.0f / 3.0f);
  return 0.5f * (__logf(1.0f + z) - __logf(1.0f - z)) * frcp(z);
}
// tanh(a) for a >= 0 via exp(-2a) in [0,1]: overflow-free, saturates to 1.
__device__ __forceinline__ float ftanh(float a) {
  const float e = __expf(-2.0f * a);
  return (1.0f - e) * frcp(1.0f + e);
}

// ---------------- K2v2: 32x32 pair tiles, 4 blocks/CU ----------------
// grid (32,32) = 1024 blocks -> 16 waves/CU (4/SIMD): latency actually hidden.
// Same proven math as R11 k2; 2x2 micro-tile; PA [N][32].
__global__ __launch_bounds__(256) void k2_pairs(
    const float* __restrict__ x, const float* __restrict__ adj,
    const float* __restrict__ aw, const float* __restrict__ bptr,
    float* __restrict__ W, float* __restrict__ PA) {
  __shared__ __align__(16) float xiT[DD * 32];  // k-major [128][32]
  __shared__ __align__(16) float xjT[DD * 32];
  __shared__ float s_pa[4][64], s_pb[4][64];
  __shared__ float s_nx2i[32], s_lft[32], s_nx2j[32], s_rgt[32];
  const int t = threadIdx.x;
  const int bi = blockIdx.y, bj = blockIdx.x;
  const int tx = t & 15, ty = t >> 4;
  const int gi0 = bi * 32 + ty * 2;
  const int gj0 = bj * 32 + tx * 2;

  // prefetch adj (2 rows x 2 cols)
  float2 ajv[2];
  ajv[0] = *(const float2*)&adj[(size_t)(gi0 + 0) * NN + gj0];
  ajv[1] = *(const float2*)&adj[(size_t)(gi0 + 1) * NN + gj0];
  const float attb = bptr[0];

  // stage k-major panels: 32 rows x 128 k each
  {
    const int r = t & 31;
    const int kq = t >> 5;  // 0..7 (16 k each)
    const float* si = x + (bi * 32 + r) * DD + kq * 16;
    const float* sj = x + (bj * 32 + r) * DD + kq * 16;
#pragma unroll
    for (int m = 0; m < 4; ++m) {
      const int k0 = kq * 16 + m * 4;
      const float4 vi = *(const float4*)(si + m * 4);
      const float4 vj = *(const float4*)(sj + m * 4);
      xiT[(k0 + 0) * 32 + r] = vi.x;
      xiT[(k0 + 1) * 32 + r] = vi.y;
      xiT[(k0 + 2) * 32 + r] = vi.z;
      xiT[(k0 + 3) * 32 + r] = vi.w;
      xjT[(k0 + 0) * 32 + r] = vj.x;
      xjT[(k0 + 1) * 32 + r] = vj.y;
      xjT[(k0 + 2) * 32 + r] = vj.z;
      xjT[(k0 + 3) * 32 + r] = vj.w;
    }
  }
  __syncthreads();

  // scalar phase: wave h covers k-range [h*32, h*32+32) for all 64 rows
  {
    const int row64 = t & 63;
    const int r = row64 & 31;
    const bool jp = (row64 >= 32);
    const int h = t >> 6;
    const float* panel = jp ? xjT : xiT;
    const float* wv = aw + (jp ? DD : 0);
    float sa = 0.0f, sb = 0.0f;
#pragma unroll 8
    for (int k = 0; k < 32; ++k) {
      const float v = panel[(h * 32 + k) * 32 + r];
      sa = fmaf(v, v, sa);
      sb = fmaf(v, wv[h * 32 + k], sb);
    }
    s_pa[h][row64] = sa;
    s_pb[h][row64] = sb;
  }
  __syncthreads();
  if (t < 64) {
    const float sa = s_pa[0][t] + s_pa[1][t] + s_pa[2][t] + s_pa[3][t];
    const float sb = s_pb[0][t] + s_pb[1][t] + s_pb[2][t] + s_pb[3][t];
    const float pn = fmaxf(fsqrt(sa), 1e-15f);
    const float hh = artanh_ratio(pn);
    const int r = t & 31;
    if (t >= 32) { s_nx2j[r] = sa; s_rgt[r] = hh * sb; }
    else         { s_nx2i[r] = sa; s_lft[r] = hh * sb; }
  }
  __syncthreads();

  // 2x2 register GEMM, 4-deep k batches
  float acc[2][2] = {};
#pragma unroll 4
  for (int kb = 0; kb < DD; kb += 4) {
    float2 A[4], B[4];
#pragma unroll
    for (int q = 0; q < 4; ++q) {
      A[q] = *(const float2*)&xiT[(kb + q) * 32 + ty * 2];
      B[q] = *(const float2*)&xjT[(kb + q) * 32 + tx * 2];
    }
#pragma unroll
    for (int q = 0; q < 4; ++q) {
      acc[0][0] = fmaf(A[q].x, B[q].x, acc[0][0]);
      acc[0][1] = fmaf(A[q].x, B[q].y, acc[0][1]);
      acc[1][0] = fmaf(A[q].y, B[q].x, acc[1][0]);
      acc[1][1] = fmaf(A[q].y, B[q].y, acc[1][1]);
    }
  }

  // pair epilogue (proven formulas)
  float ny2v[2], rv[2];
#pragma unroll
  for (int j = 0; j < 2; ++j) {
    ny2v[j] = s_nx2j[tx * 2 + j];
    rv[j] = s_rgt[tx * 2 + j];
  }
  float sua[2];
#pragma unroll
  for (int i = 0; i < 2; ++i) {
    const float xi2 = s_nx2i[ty * 2 + i];
    const float li = s_lft[ty * 2 + i];
    const float beta = 1.0f - xi2;
    const float betac = fmaxf(beta, 1e-15f);
    const float av[2] = {(i ? ajv[1].x : ajv[0].x), (i ? ajv[1].y : ajv[0].y)};
    float u2[2];
    float ua = 0.0f;
#pragma unroll
    for (int j = 0; j < 2; ++j) {
      const float s = acc[i][j];
      const float al = 1.0f - 2.0f * s + ny2v[j];
      const float den = fmaxf(1.0f - 2.0f * s + xi2 * ny2v[j], 1e-15f);
      const float rden = frcp(den);
      float s2 = fmaxf(al * al * xi2 - 2.0f * al * beta * s + beta * beta * ny2v[j], 0.0f);
      s2 = s2 * rden * rden;
      const float sn = fmaxf(fsqrt(s2), 1e-15f);
      const float G = betac * artanh_ratio(sn);
      const float sig = frcp(1.0f + __expf(-(li + rv[j] + attb)));
      const float u = sig * av[j] * G * rden;
      u2[j] = u;
      ua = fmaf(u, al, ua);
    }
    float2 st; st.x = u2[0]; st.y = u2[1];
    *(float2*)&W[(size_t)(gi0 + i) * NN + gj0] = st;
    sua[i] = ua;
  }
#pragma unroll
  for (int m = 1; m < 16; m <<= 1) {
#pragma unroll
    for (int i = 0; i < 2; ++i) sua[i] += __shfl_xor(sua[i], m, 64);
  }
  if (tx == 0) {
#pragma unroll
    for (int i = 0; i < 2; ++i) PA[(gi0 + i) * 32 + bj] = sua[i];
  }
}

// ---------------- K3v2: V-partials, grid (16,32), 2 blocks/CU ----------------
// Block (kt 0..15, rt 0..31): rows rt*32..+31, j-chunk kt*64..+63.
__global__ __launch_bounds__(256) void k3_vpart(
    const float* __restrict__ x, const float* __restrict__ W,
    float* __restrict__ Vp) {
  __shared__ __align__(16) float uT[64 * LDU];  // 9.2 KB
  __shared__ __align__(16) float xT[64 * DD];   // 32 KB
  const int t = threadIdx.x;
  const int kt = blockIdx.x, rt = blockIdx.y;
  // stage uT: 8 thr/row, 8 floats each, transposed write
  {
    const int r = t >> 3;         // 0..31
    const int c0 = (t & 7) * 8;   // 0,8,..,56
    const float* wrow = &W[(size_t)(rt * 32 + r) * NN + kt * 64 + c0];
    const float4 v0 = *(const float4*)(wrow);
    const float4 v1 = *(const float4*)(wrow + 4);
    uT[(c0 + 0) * LDU + r] = v0.x;
    uT[(c0 + 1) * LDU + r] = v0.y;
    uT[(c0 + 2) * LDU + r] = v0.z;
    uT[(c0 + 3) * LDU + r] = v0.w;
    uT[(c0 + 4) * LDU + r] = v1.x;
    uT[(c0 + 5) * LDU + r] = v1.y;
    uT[(c0 + 6) * LDU + r] = v1.z;
    uT[(c0 + 7) * LDU + r] = v1.w;
  }
  // stage xT: x rows kt*64..+63 (flat 8192 floats)
  {
    const float* xsrc = &x[(size_t)kt * 64 * DD];
#pragma unroll
    for (int p = 0; p < 8; ++p) {
      *(float4*)&xT[p * 1024 + t * 4] = *(const float4*)&xsrc[p * 1024 + t * 4];
    }
  }
  __syncthreads();
  const int tx = t & 31, ty = t >> 5;
  float acc[4][4] = {};
#pragma unroll 2
  for (int kb = 0; kb < 64; kb += 4) {
    float4 A[4], B[4];
#pragma unroll
    for (int q = 0; q < 4; ++q) {
      A[q] = *(const float4*)&uT[(kb + q) * LDU + ty * 4];
      B[q] = *(const float4*)&xT[(kb + q) * DD + tx * 4];
    }
#pragma unroll
    for (int q = 0; q < 4; ++q) {
      const float aa[4] = {A[q].x, A[q].y, A[q].z, A[q].w};
      const float bb[4] = {B[q].x, B[q].y, B[q].z, B[q].w};
#pragma unroll
      for (int i = 0; i < 4; ++i)
#pragma unroll
        for (int j = 0; j < 4; ++j) acc[i][j] = fmaf(aa[i], bb[j], acc[i][j]);
    }
  }
  const int row0 = rt * 32 + ty * 4;
#pragma unroll
  for (int i = 0; i < 4; ++i) {
    float4 s; s.x = acc[i][0]; s.y = acc[i][1]; s.z = acc[i][2]; s.w = acc[i][3];
    *(float4*)&Vp[((size_t)kt * NN + row0 + i) * DD + tx * 4] = s;
  }
}

// ---------------- K4: reduce 16 partials + expmap/proj ----------------
__global__ __launch_bounds__(256) void k4_final(
    const float* __restrict__ x, const float* __restrict__ Vp,
    const float* __restrict__ PA, float* __restrict__ out) {
  const int t = threadIdx.x;
  const int w = t >> 6;
  const int l = t & 63;
  const int row = blockIdx.x * 4 + w;

  const float2 xv = *(const float2*)&x[row * DD + 2 * l];
  const float xi0 = xv.x, xi1 = xv.y;
  float ra = xi0 * xi0 + xi1 * xi1;
#pragma unroll
  for (int m = 1; m < 64; m <<= 1) ra += __shfl_xor(ra, m, 64);
  const float nx2i = ra;

  float v0 = 0.0f, v1 = 0.0f;
#pragma unroll
  for (int kt = 0; kt < 16; ++kt) {
    const float2 vv = *(const float2*)&Vp[((size_t)kt * NN + row) * DD + 2 * l];
    v0 += vv.x;
    v1 += vv.y;
  }
  float sa = (l < 32) ? PA[row * 32 + l] : 0.0f;
#pragma unroll
  for (int m = 1; m < 64; m <<= 1) sa += __shfl_xor(sa, m, 64);

  const float beta = 1.0f - nx2i;
  const float betac = fmaxf(beta, 1e-15f);
  const float u0 = beta * v0 - sa * xi0;
  const float u1 = beta * v1 - sa * xi1;
  float p0 = u0 * u0 + u1 * u1;
  float p1 = xi0 * u0 + xi1 * u1;
#pragma unroll
  for (int m = 1; m < 64; m <<= 1) {
    p0 += __shfl_xor(p0, m, 64);
    p1 += __shfl_xor(p1, m, 64);
  }
  const float un = fmaxf(fsqrt(p0), 1e-15f);
  const float tau = ftanh(frcp(betac) * un) * frcp(un);  // tanh(0.5*lam*un)/un
  const float y2 = tau * tau * p0;
  const float xy = tau * p1;
  const float numx = 1.0f + 2.0f * xy + y2;
  const float dene = fmaxf(1.0f + 2.0f * xy + nx2i * y2, 1e-15f);
  const float rdene = frcp(dene);
  float r0 = (numx * xi0 + beta * tau * u0) * rdene;
  float r1 = (numx * xi1 + beta * tau * u1) * rdene;
  const float n2 = fmaxf(numx * numx * nx2i + 2.0f * numx * beta * xy + beta * beta * y2, 0.0f);
  const float n = fmaxf(fsqrt(n2) * rdene, 1e-15f);
  const float maxn = 1.0f - 4e-3f;  // (1-PROJ_EPS)/sqrt(c)
  if (n > maxn) {
    const float sc = maxn * frcp(n);
    r0 *= sc;
    r1 *= sc;
  }
  float2 ro; ro.x = r0; ro.y = r1;
  *(float2*)&out[row * DD + 2 * l] = ro;
}

// ---------------- Fallback: fused kernel (proven structure) ----------------
__global__ __launch_bounds__(256) void hypagg_fused(
    const float* __restrict__ x, const float* __restrict__ adj,
    const float* __restrict__ aw, const float* __restrict__ bptr,
    float* __restrict__ out) {
  __shared__ __align__(16) float xi_lds[4 * DD];
  __shared__ __align__(16) float w2_lds[DD];
  const int t = threadIdx.x;
  const int w = t >> 6;
  const int l = t & 63;
  const int row = blockIdx.x * 4 + w;

  xi_lds[t] = x[blockIdx.x * 4 * DD + t];
  xi_lds[t + 256] = x[blockIdx.x * 4 * DD + t + 256];
  if (t < DD) w2_lds[t] = aw[DD + t];
  __syncthreads();

  const float attb = bptr[0];
  const float* xi = &xi_lds[w * DD];
  const float xi0 = xi[l];
  const float xi1 = xi[l + 64];

  float ra = xi0 * xi0 + xi1 * xi1;
  float rb = xi0 * aw[l] + xi1 * aw[l + 64];
#pragma unroll
  for (int m = 1; m < 64; m <<= 1) {
    ra += __shfl_xor(ra, m, 64);
    rb += __shfl_xor(rb, m, 64);
  }
  const float nx2i = ra;
  const float beta = 1.0f - nx2i;
  const float betac = fmaxf(beta, 1e-15f);
  const float hi = artanh_ratio(fmaxf(fsqrt(nx2i), 1e-15f));
  const float lfti = hi * rb;

  float V0 = 0.0f, V1 = 0.0f, SA = 0.0f;

  for (int j0 = 0; j0 < NN; j0 += 64) {
    const int jj = j0 + l;
    const float* xj = x + jj * DD;
    float s = 0.0f, ny2 = 0.0f, rj = 0.0f;
#pragma unroll 8
    for (int k4 = 0; k4 < DD / 4; ++k4) {
      const float4 b4 = *(const float4*)(xj + k4 * 4);
      const float4 a4 = *(const float4*)(xi + k4 * 4);
      const float4 w4 = *(const float4*)(&w2_lds[k4 * 4]);
      s   = fmaf(a4.x, b4.x, fmaf(a4.y, b4.y, fmaf(a4.z, b4.z, fmaf(a4.w, b4.w, s))));
      ny2 = fmaf(b4.x, b4.x, fmaf(b4.y, b4.y, fmaf(b4.z, b4.z, fmaf(b4.w, b4.w, ny2))));
      rj  = fmaf(w4.x, b4.x, fmaf(w4.y, b4.y, fmaf(w4.z, b4.z, fmaf(w4.w, b4.w, rj))));
    }
    const float hj = artanh_ratio(fmaxf(fsqrt(ny2), 1e-15f));
    const float rgtj = hj * rj;
    const float al = 1.0f - 2.0f * s + ny2;
    const float den = fmaxf(1.0f - 2.0f * s + nx2i * ny2, 1e-15f);
    const float rden = frcp(den);
    float s2 = fmaxf(al * al * nx2i - 2.0f * al * beta * s + beta * beta * ny2, 0.0f);
    s2 = s2 * rden * rden;
    const float sn = fmaxf(fsqrt(s2), 1e-15f);
    const float G = betac * artanh_ratio(sn);
    const float sig = frcp(1.0f + __expf(-(lfti + rgtj + attb)));
    const float u = sig * adj[row * NN + jj] * G * rden;
    SA = fmaf(u, al, SA);
#pragma unroll 16
    for (int jq = 0; jq < 64; ++jq) {
      const float uq = __shfl(u, jq, 64);
      const float xd0 = x[(j0 + jq) * DD + l];
      const float xd1 = x[(j0 + jq) * DD + l + 64];
      V0 = fmaf(uq, xd0, V0);
      V1 = fmaf(uq, xd1, V1);
    }
  }

#pragma unroll
  for (int m = 1; m < 64; m <<= 1) SA += __shfl_xor(SA, m, 64);

  const float u0 = beta * V0 - SA * xi0;
  const float u1 = beta * V1 - SA * xi1;
  float p0 = u0 * u0 + u1 * u1;
  float p1 = xi0 * u0 + xi1 * u1;
#pragma unroll
  for (int m = 1; m < 64; m <<= 1) {
    p0 += __shfl_xor(p0, m, 64);
    p1 += __shfl_xor(p1, m, 64);
  }
  const float un = fmaxf(fsqrt(p0), 1e-15f);
  const float tau = ftanh(frcp(betac) * un) * frcp(un);
  const float y2 = tau * tau * p0;
  const float xy = tau * p1;
  const float numx = 1.0f + 2.0f * xy + y2;
  const float dene = fmaxf(1.0f + 2.0f * xy + nx2i * y2, 1e-15f);
  const float rdene = frcp(dene);
  float r0 = (numx * xi0 + beta * tau * u0) * rdene;
  float r1 = (numx * xi1 + beta * tau * u1) * rdene;
  const float n2 = fmaxf(numx * numx * nx2i + 2.0f * numx * beta * xy + beta * beta * y2, 0.0f);
  const float n = fmaxf(fsqrt(n2) * rdene, 1e-15f);
  const float maxn = 1.0f - 4e-3f;
  if (n > maxn) {
    const float sc = maxn * frcp(n);
    r0 *= sc;
    r1 *= sc;
  }
  out[row * DD + l] = r0;
  out[row * DD + l + 64] = r1;
}

extern "C" void kernel_launch(void* const* d_in, const int* in_sizes, int n_in,
                              void* d_out, int out_size, void* d_ws, size_t ws_size,
                              hipStream_t stream) {
  // Bind inputs BY SIZE (unique: x=131072, adj=1048576, att_w=256, att_b=1)
  const float* x = nullptr;
  const float* adj = nullptr;
  const float* aw = nullptr;
  const float* ab = nullptr;
  for (int i = 0; i < n_in; ++i) {
    switch (in_sizes[i]) {
      case NN * DD:  x   = (const float*)d_in[i]; break;
      case NN * NN:  adj = (const float*)d_in[i]; break;
      case 2 * DD:   aw  = (const float*)d_in[i]; break;
      case 1:        ab  = (const float*)d_in[i]; break;
      default: break;
    }
  }
  float* out = (float*)d_out;

  // ws layout: W [N*N] | Vp [16*N*D] | PA [N*32]
  const size_t need = ((size_t)NN * NN + 16 * (size_t)NN * DD + NN * 32) * sizeof(float);
  if (ws_size >= need) {
    float* W  = (float*)d_ws;
    float* Vp = W + (size_t)NN * NN;
    float* PA = Vp + 16 * (size_t)NN * DD;
    hipLaunchKernelGGL(k2_pairs, dim3(32, 32), dim3(256), 0, stream,
                       x, adj, aw, ab, W, PA);
    hipLaunchKernelGGL(k3_vpart, dim3(16, 32), dim3(256), 0, stream, x, W, Vp);
    hipLaunchKernelGGL(k4_final, dim3(NN / 4), dim3(256), 0, stream,
                       x, Vp, PA, out);
  } else {
    hipLaunchKernelGGL(hypagg_fused, dim3(NN / 4), dim3(256), 0, stream,
                       x, adj, aw, ab, out);
  }
}

// Round 17
// 28.208 us; speedup vs baseline: 2.6962x; 1.2115x over previous
//
#include <hip/hip_runtime.h>

#define NN 1024
#define DD 128

// ---- fast math helpers ----
// v_rcp_f32 is ~1 ulp on gfx950; NO Newton step (NR turns inf into NaN).
__device__ __forceinline__ float frcp(float x) {
  return __builtin_amdgcn_rcpf(x);
}
__device__ __forceinline__ float fsqrt(float x) {
  return __builtin_amdgcn_sqrtf(x);
}
// artanh(z)/z with reference-style clipping (z >= 0)
__device__ __forceinline__ float artanh_ratio(float z) {
  z = fminf(z, 1.0f - 1e-7f);
  if (z < 1e-4f) return 1.0f + z * z * (1.0f / 3.0f);
  return 0.5f * (__logf(1.0f + z) - __logf(1.0f - z)) * frcp(z);
}
// tanh(a) for a >= 0 via exp(-2a) in [0,1]: overflow-free, saturates to 1.
__device__ __forceinline__ float ftanh(float a) {
  const float e = __expf(-2.0f * a);
  return (1.0f - e) * frcp(1.0f + e);
}

// ---------------- K23: pair kernel + fused per-tile V GEMM ----------------
// 64x64 tile (R11's proven k2 body). After the epilogue, u goes to LDS
// (aliasing xiT) instead of W-global, and the block computes its Vp slab
// contribution u_tile[64x64] @ x_tile[64x128]: u via LDS broadcast
// (conflict-free), x_j re-read coalesced from L2. W round-trip eliminated.
__global__ __launch_bounds__(256) void k23_pairs_v(
    const float* __restrict__ x, const float* __restrict__ adj,
    const float* __restrict__ aw, const float* __restrict__ bptr,
    float* __restrict__ Vp, float* __restrict__ PA) {
  __shared__ __align__(16) float xiT[DD * 64];  // 32 KB (first 16 KB -> u_lds)
  __shared__ __align__(16) float xjT[DD * 64];  // 32 KB
  __shared__ float s_nx2i[64], s_lft[64], s_nx2j[64], s_rgt[64];
  const int t = threadIdx.x;
  const int bi = blockIdx.y, bj = blockIdx.x;
  const int tx = t & 15, ty = t >> 4;
  const int gi0 = bi * 64 + ty * 4;
  const int gj0 = bj * 64 + tx * 4;

  // prefetch adj tile rows (hides latency under k-loop)
  float4 ajv[4];
#pragma unroll
  for (int i = 0; i < 4; ++i)
    ajv[i] = *(const float4*)&adj[(size_t)(gi0 + i) * NN + gj0];
  const float attb = bptr[0];

  // stage k-major panels
  {
    const int r = t & 63;
    const int kq = t >> 6;  // k-quarter (32 k each)
    const float* si = x + (bi * 64 + r) * DD + kq * 32;
    const float* sj = x + (bj * 64 + r) * DD + kq * 32;
#pragma unroll
    for (int m = 0; m < 8; ++m) {
      const int k0 = kq * 32 + m * 4;
      const float4 vi = *(const float4*)(si + m * 4);
      const float4 vj = *(const float4*)(sj + m * 4);
      xiT[(k0 + 0) * 64 + r] = vi.x;
      xiT[(k0 + 1) * 64 + r] = vi.y;
      xiT[(k0 + 2) * 64 + r] = vi.z;
      xiT[(k0 + 3) * 64 + r] = vi.w;
      xjT[(k0 + 0) * 64 + r] = vj.x;
      xjT[(k0 + 1) * 64 + r] = vj.y;
      xjT[(k0 + 2) * 64 + r] = vj.z;
      xjT[(k0 + 3) * 64 + r] = vj.w;
    }
  }
  __syncthreads();

  // per-node scalars from staged panels (proven)
  {
    const int r = (t >> 1) & 63;
    const int h = t & 1;
    const bool jp = (t >= 128);
    const float* panel = jp ? xjT : xiT;
    const float* wv = aw + (jp ? DD : 0);
    float sa = 0.0f, sb = 0.0f;
    const int k0 = h * 64;
#pragma unroll 8
    for (int k = 0; k < 64; ++k) {
      const float v = panel[(k0 + k) * 64 + r];
      sa = fmaf(v, v, sa);
      sb = fmaf(v, wv[k0 + k], sb);
    }
    sa += __shfl_xor(sa, 1, 64);
    sb += __shfl_xor(sb, 1, 64);
    if (h == 0) {
      const float pn = fmaxf(fsqrt(sa), 1e-15f);
      const float hh = artanh_ratio(pn);
      if (jp) { s_nx2j[r] = sa; s_rgt[r] = hh * sb; }
      else    { s_nx2i[r] = sa; s_lft[r] = hh * sb; }
    }
  }
  __syncthreads();

  // S-GEMM 4x4, 4-deep k batches (proven)
  float acc[4][4] = {};
#pragma unroll 2
  for (int kb = 0; kb < DD; kb += 4) {
    float4 A[4], B[4];
#pragma unroll
    for (int q = 0; q < 4; ++q) {
      A[q] = *(const float4*)&xiT[(kb + q) * 64 + ty * 4];
      B[q] = *(const float4*)&xjT[(kb + q) * 64 + tx * 4];
    }
#pragma unroll
    for (int q = 0; q < 4; ++q) {
      const float aa[4] = {A[q].x, A[q].y, A[q].z, A[q].w};
      const float bb[4] = {B[q].x, B[q].y, B[q].z, B[q].w};
#pragma unroll
      for (int i = 0; i < 4; ++i)
#pragma unroll
        for (int j = 0; j < 4; ++j) acc[i][j] = fmaf(aa[i], bb[j], acc[i][j]);
    }
  }

  // pair epilogue (proven formulas) -> u kept in registers
  float ny2v[4], rv[4];
#pragma unroll
  for (int j = 0; j < 4; ++j) {
    ny2v[j] = s_nx2j[tx * 4 + j];
    rv[j] = s_rgt[tx * 4 + j];
  }
  float4 ureg[4];
  float sua[4];
#pragma unroll
  for (int i = 0; i < 4; ++i) {
    const float xi2 = s_nx2i[ty * 4 + i];
    const float li = s_lft[ty * 4 + i];
    const float beta = 1.0f - xi2;
    const float betac = fmaxf(beta, 1e-15f);
    const float av[4] = {ajv[i].x, ajv[i].y, ajv[i].z, ajv[i].w};
    float u4[4];
    float ua = 0.0f;
#pragma unroll
    for (int j = 0; j < 4; ++j) {
      const float s = acc[i][j];
      const float al = 1.0f - 2.0f * s + ny2v[j];
      const float den = fmaxf(1.0f - 2.0f * s + xi2 * ny2v[j], 1e-15f);
      const float rden = frcp(den);
      float s2 = fmaxf(al * al * xi2 - 2.0f * al * beta * s + beta * beta * ny2v[j], 0.0f);
      s2 = s2 * rden * rden;
      const float sn = fmaxf(fsqrt(s2), 1e-15f);
      const float G = betac * artanh_ratio(sn);
      const float sig = frcp(1.0f + __expf(-(li + rv[j] + attb)));
      const float u = sig * av[j] * G * rden;
      u4[j] = u;
      ua = fmaf(u, al, ua);
    }
    ureg[i].x = u4[0]; ureg[i].y = u4[1]; ureg[i].z = u4[2]; ureg[i].w = u4[3];
    sua[i] = ua;
  }
#pragma unroll
  for (int m = 1; m < 16; m <<= 1) {
#pragma unroll
    for (int i = 0; i < 4; ++i) sua[i] += __shfl_xor(sua[i], m, 64);
  }
  if (tx == 0) {
#pragma unroll
    for (int i = 0; i < 4; ++i) PA[(gi0 + i) * 16 + bj] = sua[i];
  }

  // write u into LDS (aliases xiT region; all xiT reads are done)
  __syncthreads();
  float* u_lds = xiT;  // [64][64], 16 KB
#pragma unroll
  for (int i = 0; i < 4; ++i)
    *(float4*)&u_lds[(ty * 4 + i) * 64 + tx * 4] = ureg[i];
  __syncthreads();

  // V GEMM: Vp[bj][gi][d] = sum_{j in tile} u[i][j] * x[j][d]
  // thread: 8 i-rows (ty2), 4 d (tx2). u: LDS broadcast; x: coalesced L2.
  {
    const int tx2 = t & 31, ty2 = t >> 5;
    const int i0 = ty2 * 8, d0 = tx2 * 4;
    float4 a8[8];
#pragma unroll
    for (int ii = 0; ii < 8; ++ii) a8[ii] = make_float4(0.0f, 0.0f, 0.0f, 0.0f);
#pragma unroll 4
    for (int jb = 0; jb < 16; ++jb) {
      const int j0 = jb * 4;
      float4 xv[4];
#pragma unroll
      for (int jj = 0; jj < 4; ++jj)
        xv[jj] = *(const float4*)&x[(size_t)(bj * 64 + j0 + jj) * DD + d0];
      float4 uv[8];
#pragma unroll
      for (int ii = 0; ii < 8; ++ii)
        uv[ii] = *(const float4*)&u_lds[(i0 + ii) * 64 + j0];
#pragma unroll
      for (int ii = 0; ii < 8; ++ii) {
        a8[ii].x = fmaf(uv[ii].x, xv[0].x, fmaf(uv[ii].y, xv[1].x, fmaf(uv[ii].z, xv[2].x, fmaf(uv[ii].w, xv[3].x, a8[ii].x))));
        a8[ii].y = fmaf(uv[ii].x, xv[0].y, fmaf(uv[ii].y, xv[1].y, fmaf(uv[ii].z, xv[2].y, fmaf(uv[ii].w, xv[3].y, a8[ii].y))));
        a8[ii].z = fmaf(uv[ii].x, xv[0].z, fmaf(uv[ii].y, xv[1].z, fmaf(uv[ii].z, xv[2].z, fmaf(uv[ii].w, xv[3].z, a8[ii].z))));
        a8[ii].w = fmaf(uv[ii].x, xv[0].w, fmaf(uv[ii].y, xv[1].w, fmaf(uv[ii].z, xv[2].w, fmaf(uv[ii].w, xv[3].w, a8[ii].w))));
      }
    }
#pragma unroll
    for (int ii = 0; ii < 8; ++ii)
      *(float4*)&Vp[((size_t)bj * NN + bi * 64 + i0 + ii) * DD + d0] = a8[ii];
  }
}

// ---------------- K4: reduce 16 slabs + expmap/proj (proven) ----------------
__global__ __launch_bounds__(256) void k4_final(
    const float* __restrict__ x, const float* __restrict__ Vp,
    const float* __restrict__ PA, float* __restrict__ out) {
  const int t = threadIdx.x;
  const int w = t >> 6;
  const int l = t & 63;
  const int row = blockIdx.x * 4 + w;

  const float2 xv = *(const float2*)&x[row * DD + 2 * l];
  const float xi0 = xv.x, xi1 = xv.y;
  float ra = xi0 * xi0 + xi1 * xi1;
#pragma unroll
  for (int m = 1; m < 64; m <<= 1) ra += __shfl_xor(ra, m, 64);
  const float nx2i = ra;

  float v0 = 0.0f, v1 = 0.0f;
#pragma unroll
  for (int kt = 0; kt < 16; ++kt) {
    const float2 vv = *(const float2*)&Vp[((size_t)kt * NN + row) * DD + 2 * l];
    v0 += vv.x;
    v1 += vv.y;
  }
  float sa = (l < 16) ? PA[row * 16 + l] : 0.0f;
#pragma unroll
  for (int m = 1; m < 64; m <<= 1) sa += __shfl_xor(sa, m, 64);

  const float beta = 1.0f - nx2i;
  const float betac = fmaxf(beta, 1e-15f);
  const float u0 = beta * v0 - sa * xi0;
  const float u1 = beta * v1 - sa * xi1;
  float p0 = u0 * u0 + u1 * u1;
  float p1 = xi0 * u0 + xi1 * u1;
#pragma unroll
  for (int m = 1; m < 64; m <<= 1) {
    p0 += __shfl_xor(p0, m, 64);
    p1 += __shfl_xor(p1, m, 64);
  }
  const float un = fmaxf(fsqrt(p0), 1e-15f);
  const float tau = ftanh(frcp(betac) * un) * frcp(un);  // tanh(0.5*lam*un)/un
  const float y2 = tau * tau * p0;
  const float xy = tau * p1;
  const float numx = 1.0f + 2.0f * xy + y2;
  const float dene = fmaxf(1.0f + 2.0f * xy + nx2i * y2, 1e-15f);
  const float rdene = frcp(dene);
  float r0 = (numx * xi0 + beta * tau * u0) * rdene;
  float r1 = (numx * xi1 + beta * tau * u1) * rdene;
  const float n2 = fmaxf(numx * numx * nx2i + 2.0f * numx * beta * xy + beta * beta * y2, 0.0f);
  const float n = fmaxf(fsqrt(n2) * rdene, 1e-15f);
  const float maxn = 1.0f - 4e-3f;  // (1-PROJ_EPS)/sqrt(c)
  if (n > maxn) {
    const float sc = maxn * frcp(n);
    r0 *= sc;
    r1 *= sc;
  }
  float2 ro; ro.x = r0; ro.y = r1;
  *(float2*)&out[row * DD + 2 * l] = ro;
}

// ---------------- Fallback: fused kernel (proven structure) ----------------
__global__ __launch_bounds__(256) void hypagg_fused(
    const float* __restrict__ x, const float* __restrict__ adj,
    const float* __restrict__ aw, const float* __restrict__ bptr,
    float* __restrict__ out) {
  __shared__ __align__(16) float xi_lds[4 * DD];
  __shared__ __align__(16) float w2_lds[DD];
  const int t = threadIdx.x;
  const int w = t >> 6;
  const int l = t & 63;
  const int row = blockIdx.x * 4 + w;

  xi_lds[t] = x[blockIdx.x * 4 * DD + t];
  xi_lds[t + 256] = x[blockIdx.x * 4 * DD + t + 256];
  if (t < DD) w2_lds[t] = aw[DD + t];
  __syncthreads();

  const float attb = bptr[0];
  const float* xi = &xi_lds[w * DD];
  const float xi0 = xi[l];
  const float xi1 = xi[l + 64];

  float ra = xi0 * xi0 + xi1 * xi1;
  float rb = xi0 * aw[l] + xi1 * aw[l + 64];
#pragma unroll
  for (int m = 1; m < 64; m <<= 1) {
    ra += __shfl_xor(ra, m, 64);
    rb += __shfl_xor(rb, m, 64);
  }
  const float nx2i = ra;
  const float beta = 1.0f - nx2i;
  const float betac = fmaxf(beta, 1e-15f);
  const float hi = artanh_ratio(fmaxf(fsqrt(nx2i), 1e-15f));
  const float lfti = hi * rb;

  float V0 = 0.0f, V1 = 0.0f, SA = 0.0f;

  for (int j0 = 0; j0 < NN; j0 += 64) {
    const int jj = j0 + l;
    const float* xj = x + jj * DD;
    float s = 0.0f, ny2 = 0.0f, rj = 0.0f;
#pragma unroll 8
    for (int k4 = 0; k4 < DD / 4; ++k4) {
      const float4 b4 = *(const float4*)(xj + k4 * 4);
      const float4 a4 = *(const float4*)(xi + k4 * 4);
      const float4 w4 = *(const float4*)(&w2_lds[k4 * 4]);
      s   = fmaf(a4.x, b4.x, fmaf(a4.y, b4.y, fmaf(a4.z, b4.z, fmaf(a4.w, b4.w, s))));
      ny2 = fmaf(b4.x, b4.x, fmaf(b4.y, b4.y, fmaf(b4.z, b4.z, fmaf(b4.w, b4.w, ny2))));
      rj  = fmaf(w4.x, b4.x, fmaf(w4.y, b4.y, fmaf(w4.z, b4.z, fmaf(w4.w, b4.w, rj))));
    }
    const float hj = artanh_ratio(fmaxf(fsqrt(ny2), 1e-15f));
    const float rgtj = hj * rj;
    const float al = 1.0f - 2.0f * s + ny2;
    const float den = fmaxf(1.0f - 2.0f * s + nx2i * ny2, 1e-15f);
    const float rden = frcp(den);
    float s2 = fmaxf(al * al * nx2i - 2.0f * al * beta * s + beta * beta * ny2, 0.0f);
    s2 = s2 * rden * rden;
    const float sn = fmaxf(fsqrt(s2), 1e-15f);
    const float G = betac * artanh_ratio(sn);
    const float sig = frcp(1.0f + __expf(-(lfti + rgtj + attb)));
    const float u = sig * adj[row * NN + jj] * G * rden;
    SA = fmaf(u, al, SA);
#pragma unroll 16
    for (int jq = 0; jq < 64; ++jq) {
      const float uq = __shfl(u, jq, 64);
      const float xd0 = x[(j0 + jq) * DD + l];
      const float xd1 = x[(j0 + jq) * DD + l + 64];
      V0 = fmaf(uq, xd0, V0);
      V1 = fmaf(uq, xd1, V1);
    }
  }

#pragma unroll
  for (int m = 1; m < 64; m <<= 1) SA += __shfl_xor(SA, m, 64);

  const float u0 = beta * V0 - SA * xi0;
  const float u1 = beta * V1 - SA * xi1;
  float p0 = u0 * u0 + u1 * u1;
  float p1 = xi0 * u0 + xi1 * u1;
#pragma unroll
  for (int m = 1; m < 64; m <<= 1) {
    p0 += __shfl_xor(p0, m, 64);
    p1 += __shfl_xor(p1, m, 64);
  }
  const float un = fmaxf(fsqrt(p0), 1e-15f);
  const float tau = ftanh(frcp(betac) * un) * frcp(un);
  const float y2 = tau * tau * p0;
  const float xy = tau * p1;
  const float numx = 1.0f + 2.0f * xy + y2;
  const float dene = fmaxf(1.0f + 2.0f * xy + nx2i * y2, 1e-15f);
  const float rdene = frcp(dene);
  float r0 = (numx * xi0 + beta * tau * u0) * rdene;
  float r1 = (numx * xi1 + beta * tau * u1) * rdene;
  const float n2 = fmaxf(numx * numx * nx2i + 2.0f * numx * beta * xy + beta * beta * y2, 0.0f);
  const float n = fmaxf(fsqrt(n2) * rdene, 1e-15f);
  const float maxn = 1.0f - 4e-3f;
  if (n > maxn) {
    const float sc = maxn * frcp(n);
    r0 *= sc;
    r1 *= sc;
  }
  out[row * DD + l] = r0;
  out[row * DD + l + 64] = r1;
}

extern "C" void kernel_launch(void* const* d_in, const int* in_sizes, int n_in,
                              void* d_out, int out_size, void* d_ws, size_t ws_size,
                              hipStream_t stream) {
  // Bind inputs BY SIZE (unique: x=131072, adj=1048576, att_w=256, att_b=1)
  const float* x = nullptr;
  const float* adj = nullptr;
  const float* aw = nullptr;
  const float* ab = nullptr;
  for (int i = 0; i < n_in; ++i) {
    switch (in_sizes[i]) {
      case NN * DD:  x   = (const float*)d_in[i]; break;
      case NN * NN:  adj = (const float*)d_in[i]; break;
      case 2 * DD:   aw  = (const float*)d_in[i]; break;
      case 1:        ab  = (const float*)d_in[i]; break;
      default: break;
    }
  }
  float* out = (float*)d_out;

  // ws layout: Vp [16*N*D] | PA [N*16]
  const size_t need = (16 * (size_t)NN * DD + NN * 16) * sizeof(float);
  if (ws_size >= need) {
    float* Vp = (float*)d_ws;
    float* PA = Vp + 16 * (size_t)NN * DD;
    hipLaunchKernelGGL(k23_pairs_v, dim3(16, 16), dim3(256), 0, stream,
                       x, adj, aw, ab, Vp, PA);
    hipLaunchKernelGGL(k4_final, dim3(NN / 4), dim3(256), 0, stream,
                       x, Vp, PA, out);
  } else {
    hipLaunchKernelGGL(hypagg_fused, dim3(NN / 4), dim3(256), 0, stream,
                       x, adj, aw, ab, out);
  }
}

// Round 18
// 28.138 us; speedup vs baseline: 2.7029x; 1.0025x over previous
//
#include <hip/hip_runtime.h>

#define NN 1024
#define DD 128

// ---- fast math helpers ----
// v_rcp_f32 is ~1 ulp on gfx950; NO Newton step (NR turns inf into NaN).
__device__ __forceinline__ float frcp(float x) {
  return __builtin_amdgcn_rcpf(x);
}
__device__ __forceinline__ float fsqrt(float x) {
  return __builtin_amdgcn_sqrtf(x);
}
// artanh(z)/z with reference-style clipping (z >= 0)
__device__ __forceinline__ float artanh_ratio(float z) {
  z = fminf(z, 1.0f - 1e-7f);
  if (z < 1e-4f) return 1.0f + z * z * (1.0f / 3.0f);
  return 0.5f * (__logf(1.0f + z) - __logf(1.0f - z)) * frcp(z);
}
// tanh(a) for a >= 0 via exp(-2a) in [0,1]: overflow-free, saturates to 1.
__device__ __forceinline__ float ftanh(float a) {
  const float e = __expf(-2.0f * a);
  return (1.0f - e) * frcp(1.0f + e);
}

// ---------------- K23: pair kernel + fused V GEMM, 512 threads ----------------
// Same proven 64x64-tile math as R17, spread over 8 waves (2/SIMD) to halve
// latency exposure. S-GEMM micro-tile 2x4; V-GEMM 4 rows x 4 d per thread.
__global__ __launch_bounds__(512) void k23_pairs_v(
    const float* __restrict__ x, const float* __restrict__ adj,
    const float* __restrict__ aw, const float* __restrict__ bptr,
    float* __restrict__ Vp, float* __restrict__ PA) {
  __shared__ __align__(16) float xiT[DD * 64];  // 32 KB (aliased to u_lds later)
  __shared__ __align__(16) float xjT[DD * 64];  // 32 KB
  __shared__ float s_nx2i[64], s_lft[64], s_nx2j[64], s_rgt[64];
  const int t = threadIdx.x;
  const int bi = blockIdx.y, bj = blockIdx.x;
  const int tx = t & 15;        // j-quad (4 cols)
  const int ty = t >> 4;        // 0..31, i-pair (2 rows)
  const int gi0 = bi * 64 + ty * 2;
  const int gj0 = bj * 64 + tx * 4;

  // prefetch adj (2 rows x 4 cols)
  float4 ajv[2];
#pragma unroll
  for (int i = 0; i < 2; ++i)
    ajv[i] = *(const float4*)&adj[(size_t)(gi0 + i) * NN + gj0];
  const float attb = bptr[0];

  // stage k-major panels: thread -> row (t&63), k-eighth (t>>6)
  {
    const int r = t & 63;
    const int kq = t >> 6;  // 0..7, 16 k each
    const float* si = x + (bi * 64 + r) * DD + kq * 16;
    const float* sj = x + (bj * 64 + r) * DD + kq * 16;
#pragma unroll
    for (int m = 0; m < 4; ++m) {
      const int k0 = kq * 16 + m * 4;
      const float4 vi = *(const float4*)(si + m * 4);
      const float4 vj = *(const float4*)(sj + m * 4);
      xiT[(k0 + 0) * 64 + r] = vi.x;
      xiT[(k0 + 1) * 64 + r] = vi.y;
      xiT[(k0 + 2) * 64 + r] = vi.z;
      xiT[(k0 + 3) * 64 + r] = vi.w;
      xjT[(k0 + 0) * 64 + r] = vj.x;
      xjT[(k0 + 1) * 64 + r] = vj.y;
      xjT[(k0 + 2) * 64 + r] = vj.z;
      xjT[(k0 + 3) * 64 + r] = vj.w;
    }
  }
  __syncthreads();

  // per-node scalars: 4 threads per row (k split 4x32), shfl_xor(1,2) combine
  {
    const int r = (t >> 2) & 63;
    const int h = t & 3;
    const bool jp = (t >= 256);
    const float* panel = jp ? xjT : xiT;
    const float* wv = aw + (jp ? DD : 0);
    float sa = 0.0f, sb = 0.0f;
    const int k0 = h * 32;
#pragma unroll 8
    for (int k = 0; k < 32; ++k) {
      const float v = panel[(k0 + k) * 64 + r];
      sa = fmaf(v, v, sa);
      sb = fmaf(v, wv[k0 + k], sb);
    }
    sa += __shfl_xor(sa, 1, 64);
    sb += __shfl_xor(sb, 1, 64);
    sa += __shfl_xor(sa, 2, 64);
    sb += __shfl_xor(sb, 2, 64);
    if (h == 0) {
      const float pn = fmaxf(fsqrt(sa), 1e-15f);
      const float hh = artanh_ratio(pn);
      if (jp) { s_nx2j[r] = sa; s_rgt[r] = hh * sb; }
      else    { s_nx2i[r] = sa; s_lft[r] = hh * sb; }
    }
  }
  __syncthreads();

  // S-GEMM 2x4, 4-deep k batches (proven pattern)
  float acc[2][4] = {};
#pragma unroll 2
  for (int kb = 0; kb < DD; kb += 4) {
    float2 A[4];
    float4 B[4];
#pragma unroll
    for (int q = 0; q < 4; ++q) {
      A[q] = *(const float2*)&xiT[(kb + q) * 64 + ty * 2];
      B[q] = *(const float4*)&xjT[(kb + q) * 64 + tx * 4];
    }
#pragma unroll
    for (int q = 0; q < 4; ++q) {
      acc[0][0] = fmaf(A[q].x, B[q].x, acc[0][0]);
      acc[0][1] = fmaf(A[q].x, B[q].y, acc[0][1]);
      acc[0][2] = fmaf(A[q].x, B[q].z, acc[0][2]);
      acc[0][3] = fmaf(A[q].x, B[q].w, acc[0][3]);
      acc[1][0] = fmaf(A[q].y, B[q].x, acc[1][0]);
      acc[1][1] = fmaf(A[q].y, B[q].y, acc[1][1]);
      acc[1][2] = fmaf(A[q].y, B[q].z, acc[1][2]);
      acc[1][3] = fmaf(A[q].y, B[q].w, acc[1][3]);
    }
  }

  // pair epilogue (proven formulas) -> u kept in registers
  float ny2v[4], rv[4];
#pragma unroll
  for (int j = 0; j < 4; ++j) {
    ny2v[j] = s_nx2j[tx * 4 + j];
    rv[j] = s_rgt[tx * 4 + j];
  }
  float4 ureg[2];
  float sua[2];
#pragma unroll
  for (int i = 0; i < 2; ++i) {
    const float xi2 = s_nx2i[ty * 2 + i];
    const float li = s_lft[ty * 2 + i];
    const float beta = 1.0f - xi2;
    const float betac = fmaxf(beta, 1e-15f);
    const float av[4] = {ajv[i].x, ajv[i].y, ajv[i].z, ajv[i].w};
    float u4[4];
    float ua = 0.0f;
#pragma unroll
    for (int j = 0; j < 4; ++j) {
      const float s = acc[i][j];
      const float al = 1.0f - 2.0f * s + ny2v[j];
      const float den = fmaxf(1.0f - 2.0f * s + xi2 * ny2v[j], 1e-15f);
      const float rden = frcp(den);
      float s2 = fmaxf(al * al * xi2 - 2.0f * al * beta * s + beta * beta * ny2v[j], 0.0f);
      s2 = s2 * rden * rden;
      const float sn = fmaxf(fsqrt(s2), 1e-15f);
      const float G = betac * artanh_ratio(sn);
      const float sig = frcp(1.0f + __expf(-(li + rv[j] + attb)));
      const float u = sig * av[j] * G * rden;
      u4[j] = u;
      ua = fmaf(u, al, ua);
    }
    ureg[i].x = u4[0]; ureg[i].y = u4[1]; ureg[i].z = u4[2]; ureg[i].w = u4[3];
    sua[i] = ua;
  }
#pragma unroll
  for (int m = 1; m < 16; m <<= 1) {
#pragma unroll
    for (int i = 0; i < 2; ++i) sua[i] += __shfl_xor(sua[i], m, 64);
  }
  if (tx == 0) {
#pragma unroll
    for (int i = 0; i < 2; ++i) PA[(gi0 + i) * 16 + bj] = sua[i];
  }

  // write u into LDS (aliases xiT; all xiT reads done)
  __syncthreads();
  float* u_lds = xiT;  // [64][64]
#pragma unroll
  for (int i = 0; i < 2; ++i)
    *(float4*)&u_lds[(ty * 2 + i) * 64 + tx * 4] = ureg[i];
  __syncthreads();

  // V GEMM: Vp[bj][gi][d] = sum_j u[i][j] * x[j][d]
  // thread: 4 i-rows (ty2 0..15), 4 d (tx2 0..31). u: LDS broadcast; x: L2.
  {
    const int tx2 = t & 31, ty2 = t >> 5;
    const int i0 = ty2 * 4, d0 = tx2 * 4;
    float4 a4[4];
#pragma unroll
    for (int ii = 0; ii < 4; ++ii) a4[ii] = make_float4(0.0f, 0.0f, 0.0f, 0.0f);
#pragma unroll 4
    for (int jb = 0; jb < 16; ++jb) {
      const int j0 = jb * 4;
      float4 xv[4];
#pragma unroll
      for (int jj = 0; jj < 4; ++jj)
        xv[jj] = *(const float4*)&x[(size_t)(bj * 64 + j0 + jj) * DD + d0];
      float4 uv[4];
#pragma unroll
      for (int ii = 0; ii < 4; ++ii)
        uv[ii] = *(const float4*)&u_lds[(i0 + ii) * 64 + j0];
#pragma unroll
      for (int ii = 0; ii < 4; ++ii) {
        a4[ii].x = fmaf(uv[ii].x, xv[0].x, fmaf(uv[ii].y, xv[1].x, fmaf(uv[ii].z, xv[2].x, fmaf(uv[ii].w, xv[3].x, a4[ii].x))));
        a4[ii].y = fmaf(uv[ii].x, xv[0].y, fmaf(uv[ii].y, xv[1].y, fmaf(uv[ii].z, xv[2].y, fmaf(uv[ii].w, xv[3].y, a4[ii].y))));
        a4[ii].z = fmaf(uv[ii].x, xv[0].z, fmaf(uv[ii].y, xv[1].z, fmaf(uv[ii].z, xv[2].z, fmaf(uv[ii].w, xv[3].z, a4[ii].z))));
        a4[ii].w = fmaf(uv[ii].x, xv[0].w, fmaf(uv[ii].y, xv[1].w, fmaf(uv[ii].z, xv[2].w, fmaf(uv[ii].w, xv[3].w, a4[ii].w))));
      }
    }
#pragma unroll
    for (int ii = 0; ii < 4; ++ii)
      *(float4*)&Vp[((size_t)bj * NN + bi * 64 + i0 + ii) * DD + d0] = a4[ii];
  }
}

// ---------------- K4: reduce 16 slabs + expmap/proj (proven) ----------------
__global__ __launch_bounds__(256) void k4_final(
    const float* __restrict__ x, const float* __restrict__ Vp,
    const float* __restrict__ PA, float* __restrict__ out) {
  const int t = threadIdx.x;
  const int w = t >> 6;
  const int l = t & 63;
  const int row = blockIdx.x * 4 + w;

  const float2 xv = *(const float2*)&x[row * DD + 2 * l];
  const float xi0 = xv.x, xi1 = xv.y;
  float ra = xi0 * xi0 + xi1 * xi1;
#pragma unroll
  for (int m = 1; m < 64; m <<= 1) ra += __shfl_xor(ra, m, 64);
  const float nx2i = ra;

  float v0 = 0.0f, v1 = 0.0f;
#pragma unroll
  for (int kt = 0; kt < 16; ++kt) {
    const float2 vv = *(const float2*)&Vp[((size_t)kt * NN + row) * DD + 2 * l];
    v0 += vv.x;
    v1 += vv.y;
  }
  float sa = (l < 16) ? PA[row * 16 + l] : 0.0f;
#pragma unroll
  for (int m = 1; m < 64; m <<= 1) sa += __shfl_xor(sa, m, 64);

  const float beta = 1.0f - nx2i;
  const float betac = fmaxf(beta, 1e-15f);
  const float u0 = beta * v0 - sa * xi0;
  const float u1 = beta * v1 - sa * xi1;
  float p0 = u0 * u0 + u1 * u1;
  float p1 = xi0 * u0 + xi1 * u1;
#pragma unroll
  for (int m = 1; m < 64; m <<= 1) {
    p0 += __shfl_xor(p0, m, 64);
    p1 += __shfl_xor(p1, m, 64);
  }
  const float un = fmaxf(fsqrt(p0), 1e-15f);
  const float tau = ftanh(frcp(betac) * un) * frcp(un);  // tanh(0.5*lam*un)/un
  const float y2 = tau * tau * p0;
  const float xy = tau * p1;
  const float numx = 1.0f + 2.0f * xy + y2;
  const float dene = fmaxf(1.0f + 2.0f * xy + nx2i * y2, 1e-15f);
  const float rdene = frcp(dene);
  float r0 = (numx * xi0 + beta * tau * u0) * rdene;
  float r1 = (numx * xi1 + beta * tau * u1) * rdene;
  const float n2 = fmaxf(numx * numx * nx2i + 2.0f * numx * beta * xy + beta * beta * y2, 0.0f);
  const float n = fmaxf(fsqrt(n2) * rdene, 1e-15f);
  const float maxn = 1.0f - 4e-3f;  // (1-PROJ_EPS)/sqrt(c)
  if (n > maxn) {
    const float sc = maxn * frcp(n);
    r0 *= sc;
    r1 *= sc;
  }
  float2 ro; ro.x = r0; ro.y = r1;
  *(float2*)&out[row * DD + 2 * l] = ro;
}

// ---------------- Fallback: fused kernel (proven structure) ----------------
__global__ __launch_bounds__(256) void hypagg_fused(
    const float* __restrict__ x, const float* __restrict__ adj,
    const float* __restrict__ aw, const float* __restrict__ bptr,
    float* __restrict__ out) {
  __shared__ __align__(16) float xi_lds[4 * DD];
  __shared__ __align__(16) float w2_lds[DD];
  const int t = threadIdx.x;
  const int w = t >> 6;
  const int l = t & 63;
  const int row = blockIdx.x * 4 + w;

  xi_lds[t] = x[blockIdx.x * 4 * DD + t];
  xi_lds[t + 256] = x[blockIdx.x * 4 * DD + t + 256];
  if (t < DD) w2_lds[t] = aw[DD + t];
  __syncthreads();

  const float attb = bptr[0];
  const float* xi = &xi_lds[w * DD];
  const float xi0 = xi[l];
  const float xi1 = xi[l + 64];

  float ra = xi0 * xi0 + xi1 * xi1;
  float rb = xi0 * aw[l] + xi1 * aw[l + 64];
#pragma unroll
  for (int m = 1; m < 64; m <<= 1) {
    ra += __shfl_xor(ra, m, 64);
    rb += __shfl_xor(rb, m, 64);
  }
  const float nx2i = ra;
  const float beta = 1.0f - nx2i;
  const float betac = fmaxf(beta, 1e-15f);
  const float hi = artanh_ratio(fmaxf(fsqrt(nx2i), 1e-15f));
  const float lfti = hi * rb;

  float V0 = 0.0f, V1 = 0.0f, SA = 0.0f;

  for (int j0 = 0; j0 < NN; j0 += 64) {
    const int jj = j0 + l;
    const float* xj = x + jj * DD;
    float s = 0.0f, ny2 = 0.0f, rj = 0.0f;
#pragma unroll 8
    for (int k4 = 0; k4 < DD / 4; ++k4) {
      const float4 b4 = *(const float4*)(xj + k4 * 4);
      const float4 a4 = *(const float4*)(xi + k4 * 4);
      const float4 w4 = *(const float4*)(&w2_lds[k4 * 4]);
      s   = fmaf(a4.x, b4.x, fmaf(a4.y, b4.y, fmaf(a4.z, b4.z, fmaf(a4.w, b4.w, s))));
      ny2 = fmaf(b4.x, b4.x, fmaf(b4.y, b4.y, fmaf(b4.z, b4.z, fmaf(b4.w, b4.w, ny2))));
      rj  = fmaf(w4.x, b4.x, fmaf(w4.y, b4.y, fmaf(w4.z, b4.z, fmaf(w4.w, b4.w, rj))));
    }
    const float hj = artanh_ratio(fmaxf(fsqrt(ny2), 1e-15f));
    const float rgtj = hj * rj;
    const float al = 1.0f - 2.0f * s + ny2;
    const float den = fmaxf(1.0f - 2.0f * s + nx2i * ny2, 1e-15f);
    const float rden = frcp(den);
    float s2 = fmaxf(al * al * nx2i - 2.0f * al * beta * s + beta * beta * ny2, 0.0f);
    s2 = s2 * rden * rden;
    const float sn = fmaxf(fsqrt(s2), 1e-15f);
    const float G = betac * artanh_ratio(sn);
    const float sig = frcp(1.0f + __expf(-(lfti + rgtj + attb)));
    const float u = sig * adj[row * NN + jj] * G * rden;
    SA = fmaf(u, al, SA);
#pragma unroll 16
    for (int jq = 0; jq < 64; ++jq) {
      const float uq = __shfl(u, jq, 64);
      const float xd0 = x[(j0 + jq) * DD + l];
      const float xd1 = x[(j0 + jq) * DD + l + 64];
      V0 = fmaf(uq, xd0, V0);
      V1 = fmaf(uq, xd1, V1);
    }
  }

#pragma unroll
  for (int m = 1; m < 64; m <<= 1) SA += __shfl_xor(SA, m, 64);

  const float u0 = beta * V0 - SA * xi0;
  const float u1 = beta * V1 - SA * xi1;
  float p0 = u0 * u0 + u1 * u1;
  float p1 = xi0 * u0 + xi1 * u1;
#pragma unroll
  for (int m = 1; m < 64; m <<= 1) {
    p0 += __shfl_xor(p0, m, 64);
    p1 += __shfl_xor(p1, m, 64);
  }
  const float un = fmaxf(fsqrt(p0), 1e-15f);
  const float tau = ftanh(frcp(betac) * un) * frcp(un);
  const float y2 = tau * tau * p0;
  const float xy = tau * p1;
  const float numx = 1.0f + 2.0f * xy + y2;
  const float dene = fmaxf(1.0f + 2.0f * xy + nx2i * y2, 1e-15f);
  const float rdene = frcp(dene);
  float r0 = (numx * xi0 + beta * tau * u0) * rdene;
  float r1 = (numx * xi1 + beta * tau * u1) * rdene;
  const float n2 = fmaxf(numx * numx * nx2i + 2.0f * numx * beta * xy + beta * beta * y2, 0.0f);
  const float n = fmaxf(fsqrt(n2) * rdene, 1e-15f);
  const float maxn = 1.0f - 4e-3f;
  if (n > maxn) {
    const float sc = maxn * frcp(n);
    r0 *= sc;
    r1 *= sc;
  }
  out[row * DD + l] = r0;
  out[row * DD + l + 64] = r1;
}

extern "C" void kernel_launch(void* const* d_in, const int* in_sizes, int n_in,
                              void* d_out, int out_size, void* d_ws, size_t ws_size,
                              hipStream_t stream) {
  // Bind inputs BY SIZE (unique: x=131072, adj=1048576, att_w=256, att_b=1)
  const float* x = nullptr;
  const float* adj = nullptr;
  const float* aw = nullptr;
  const float* ab = nullptr;
  for (int i = 0; i < n_in; ++i) {
    switch (in_sizes[i]) {
      case NN * DD:  x   = (const float*)d_in[i]; break;
      case NN * NN:  adj = (const float*)d_in[i]; break;
      case 2 * DD:   aw  = (const float*)d_in[i]; break;
      case 1:        ab  = (const float*)d_in[i]; break;
      default: break;
    }
  }
  float* out = (float*)d_out;

  // ws layout: Vp [16*N*D] | PA [N*16]
  const size_t need = (16 * (size_t)NN * DD + NN * 16) * sizeof(float);
  if (ws_size >= need) {
    float* Vp = (float*)d_ws;
    float* PA = Vp + 16 * (size_t)NN * DD;
    hipLaunchKernelGGL(k23_pairs_v, dim3(16, 16), dim3(512), 0, stream,
                       x, adj, aw, ab, Vp, PA);
    hipLaunchKernelGGL(k4_final, dim3(NN / 4), dim3(256), 0, stream,
                       x, Vp, PA, out);
  } else {
    hipLaunchKernelGGL(hypagg_fused, dim3(NN / 4), dim3(256), 0, stream,
                       x, adj, aw, ab, out);
  }
}